// Round 13
// baseline (339.396 us; speedup 1.0000x reference)
//
#include <hip/hip_runtime.h>
#include <hip/hip_bf16.h>
#include <cstdint>

#define TOKENS 8192
#define IN_F   4096
#define OUT_F  4096

#define BM 256
#define BN 256
#define BK 64
#define NT (IN_F / BK)   // 64 K-tiles
#define THREADS 512

typedef __attribute__((ext_vector_type(8))) short bf16x8;
typedef __attribute__((ext_vector_type(4))) float f32x4;
typedef __attribute__((ext_vector_type(16))) float f32x16;

#define GLOBAL_AS __attribute__((address_space(1)))
#define LDS_AS    __attribute__((address_space(3)))

#define BARRIER() __builtin_amdgcn_s_barrier()
#define LGKM(n)   do { asm volatile("s_waitcnt lgkmcnt(" #n ")"); \
                       __builtin_amdgcn_sched_barrier(0); } while (0)
#define VMCNT(n)  do { asm volatile("s_waitcnt vmcnt(" #n ")"); \
                       __builtin_amdgcn_sched_barrier(0); } while (0)

__device__ __forceinline__ unsigned short f2bf(float f) {
  union { float f; unsigned int u; } v;
  v.f = f;
  unsigned int r = 0x7FFFu + ((v.u >> 16) & 1u);
  return (unsigned short)((v.u + r) >> 16);
}

__device__ __forceinline__ float softplus_f(float x) {
  return log1pf(expf(x));
}

// ---------------- fused prep kernel ----------------

#define NW4 ((long long)OUT_F * IN_F / 4)
#define NX4 ((long long)TOKENS * IN_F / 4)
#define NB4 (OUT_F / 4)

__global__ void prep_kernel(const float* __restrict__ x,
                            const float* __restrict__ wmu,
                            const float* __restrict__ wrho,
                            const float* __restrict__ weps,
                            const float* __restrict__ bmu,
                            const float* __restrict__ brho,
                            const float* __restrict__ beps,
                            unsigned short* __restrict__ xb,
                            unsigned short* __restrict__ wb,
                            float* __restrict__ bias) {
  long long i = (long long)blockIdx.x * blockDim.x + threadIdx.x;
  long long stride = (long long)gridDim.x * blockDim.x;
  const long long total = NW4 + NX4 + NB4;
  for (; i < total; i += stride) {
    if (i < NW4) {
      float4 m = reinterpret_cast<const float4*>(wmu)[i];
      float4 r = reinterpret_cast<const float4*>(wrho)[i];
      float4 e = reinterpret_cast<const float4*>(weps)[i];
      ushort4 o;
      o.x = f2bf(fmaf(softplus_f(r.x), e.x, m.x));
      o.y = f2bf(fmaf(softplus_f(r.y), e.y, m.y));
      o.z = f2bf(fmaf(softplus_f(r.z), e.z, m.z));
      o.w = f2bf(fmaf(softplus_f(r.w), e.w, m.w));
      reinterpret_cast<ushort4*>(wb)[i] = o;
    } else if (i < NW4 + NX4) {
      long long j = i - NW4;
      float4 m = reinterpret_cast<const float4*>(x)[j];
      ushort4 o;
      o.x = f2bf(m.x); o.y = f2bf(m.y); o.z = f2bf(m.z); o.w = f2bf(m.w);
      reinterpret_cast<ushort4*>(xb)[j] = o;
    } else {
      long long j = i - NW4 - NX4;
      float4 m = reinterpret_cast<const float4*>(bmu)[j];
      float4 r = reinterpret_cast<const float4*>(brho)[j];
      float4 e = reinterpret_cast<const float4*>(beps)[j];
      float4 o;
      o.x = fmaf(softplus_f(r.x), e.x, m.x);
      o.y = fmaf(softplus_f(r.y), e.y, m.y);
      o.z = fmaf(softplus_f(r.z), e.z, m.z);
      o.w = fmaf(softplus_f(r.w), e.w, m.w);
      reinterpret_cast<float4*>(bias)[j] = o;
    }
  }
}

// ---------------- GEMM: 256x256, r9 free-flow skeleton + 32x32x16 MFMA ----------------
// r13: MFMA shape 16x16x32 -> 32x32x16 (ubench 2075 -> 2382 TF: -316 cyc/tile
// on the MFMA side; instruction count halves 64->32/wave/tile). Read volume
// unchanged (24 x b128/wave/tile). Operand mapping (derived consistent with
// the correctness-passing 16x16 mapping): A/B lane l holds row/col = l&31,
// k = (l>>5)*8 + j; C/D col=lane&31, row=(reg&3)+8*(reg>>2)+4*(lane>>5)
// [guide m74/m101-verified]. Everything else verbatim r9:
//   - A ring 3 x 32 KiB + B ring 2 x 32 KiB (160 KiB), 8 waves (2M x 4N),
//     per-wave out 128x64 (now 4x2 tiles of 32x32).
//   - B read ONCE per tile into regs (8 frags) -> B-slot hazard proof as r9.
//   - free-flow kstep pipeline with counted LGKM; 2 barriers/tile;
//     VMCNT(6) boundary publish (ledger identical to r9).
// LDS swizzle: chunk ^= (row & 7) (row&7 == lane&7 since block bases are
// multiples of 32) via pre-swizzled global source + XOR on ds_read.

__global__ __launch_bounds__(THREADS, 2) void gemm_bt_kernel(
    const unsigned short* __restrict__ A,   // [TOKENS][IN_F] bf16
    const unsigned short* __restrict__ B,   // [OUT_F][IN_F] bf16
    const float* __restrict__ bias,         // [OUT_F]
    float* __restrict__ C)                  // [TOKENS][OUT_F]
{
  __shared__ unsigned short lds[5 * 16384]; // 160 KiB

  const int tid  = threadIdx.x;
  const int lane = tid & 63;
  const int wave = tid >> 6;   // 0..7
  const int wm   = wave >> 2;  // 0..1
  const int wn   = wave & 3;   // 0..3

  // XCD-aware bijective block swizzle (512 = 8 XCD chunks x 64)
  const int bid = blockIdx.x;
  const int wg  = (bid & 7) * 64 + (bid >> 3);
  const int ch  = wg >> 6;
  const int idx = wg & 63;
  const int bm  = (ch >> 1) * 8 + (idx >> 3);  // 0..31
  const int bn  = (ch & 1) * 8 + (idx & 7);    // 0..15

  const int lane31 = lane & 31;
  // per-kstep read offset: row part (lane31*64) + swizzled 16B chunk
  // data chunk = ks*2 + (lane>>5); lds chunk = dchunk ^ (row&7) = ^ (lane&7)
  int off[4];
#pragma unroll
  for (int ks = 0; ks < 4; ++ks)
    off[ks] = lane31 * 64 + (((ks * 2 + (lane >> 5)) ^ (lane & 7)) << 3);

  // staging: per-lane pre-swizzled global source (verbatim r9)
  const int srow = lane >> 3;                  // 0..7
  const int scol = ((lane & 7) ^ srow) * 8;    // swizzled 16B chunk -> elems
  const unsigned short* Asrc = A + (size_t)(bm * BM + wave * 16 + srow) * IN_F + scol;
  const unsigned short* Bsrc = B + (size_t)(bn * BN + wave * 16 + srow) * IN_F + scol;

  f32x16 acc[4][2] = {};   // 128 AGPR: [row-block 32][col-block 32]

  auto stA = [&](int slot, int half, int t) {
    unsigned short* dst = &lds[slot * 16384 + half * 8192 + wave * 1024];
    const unsigned short* g = Asrc + (size_t)(half * 128) * IN_F + t * BK;
    __builtin_amdgcn_global_load_lds((const GLOBAL_AS void*)g,
                                     (LDS_AS void*)dst, 16, 0, 0);
    __builtin_amdgcn_global_load_lds((const GLOBAL_AS void*)(g + (size_t)8 * IN_F),
                                     (LDS_AS void*)(dst + 512), 16, 0, 0);
  };
  auto stB = [&](int slot, int half, int t) {
    unsigned short* dst = &lds[49152 + slot * 16384 + half * 8192 + wave * 1024];
    const unsigned short* g = Bsrc + (size_t)(half * 128) * IN_F + t * BK;
    __builtin_amdgcn_global_load_lds((const GLOBAL_AS void*)g,
                                     (LDS_AS void*)dst, 16, 0, 0);
    __builtin_amdgcn_global_load_lds((const GLOBAL_AS void*)(g + (size_t)8 * IN_F),
                                     (LDS_AS void*)(dst + 512), 16, 0, 0);
  };

  // A frags for one kstep: 4 row-blocks of 32
  auto rdA = [&](const unsigned short* Ar, int ks, bf16x8 (&av)[4]) {
#pragma unroll
    for (int m = 0; m < 4; ++m)
      av[m] = *reinterpret_cast<const bf16x8*>(Ar + (wm * 128 + m * 32) * 64 + off[ks]);
  };
  // all B frags for the tile: 2 col-blocks x 4 ksteps
  bf16x8 bv[2][4];
  auto rdB = [&](const unsigned short* Br) {
#pragma unroll
    for (int n = 0; n < 2; ++n)
#pragma unroll
      for (int ks = 0; ks < 4; ++ks)
        bv[n][ks] = *reinterpret_cast<const bf16x8*>(Br + (wn * 64 + n * 32) * 64 + off[ks]);
  };
  auto mfma8 = [&](bf16x8 (&av)[4], int ks) {
    __builtin_amdgcn_s_setprio(1);
#pragma unroll
    for (int m = 0; m < 4; ++m)
#pragma unroll
      for (int n = 0; n < 2; ++n)
        acc[m][n] = __builtin_amdgcn_mfma_f32_32x32x16_bf16(av[m], bv[n][ks], acc[m][n], 0, 0, 0);
    __builtin_amdgcn_s_setprio(0);
  };

  // prologue: stage t0 fully, then t1 fully; wait t0 (8 newest stay in flight)
  stA(0, 0, 0); stA(0, 1, 0); stB(0, 0, 0); stB(0, 1, 0);
  stA(1, 0, 1); stA(1, 1, 1); stB(1, 0, 1); stB(1, 1, 1);
  VMCNT(8);
  BARRIER();

  int aslot = 0, bslot = 0;
  for (int t = 0; t < NT; ++t) {
    const unsigned short* As = &lds[aslot * 16384];
    const unsigned short* Bs = &lds[49152 + bslot * 16384];
    int a2 = aslot + 2; if (a2 >= 3) a2 -= 3;   // A slot of tile t+2
    const bool pf = (t + 2 < NT);
    bf16x8 av0[4], av1[4];

    // ---- free-flow body: reads run one kstep ahead of MFMA ----
    rdB(Bs);                                     // 8 ds
    rdA(As, 0, av0);                             // +4 = 12
    if (pf) { stA(a2, 0, t + 2); stA(a2, 1, t + 2); }   // vm +4
    rdA(As, 1, av1);                             // +4 = 16 outstanding
    LGKM(4);                                     // B + ks0 ready; ks1 in flight
    mfma8(av0, 0);                               // ks0
    BARRIER();   // bar1: all waves' B reads drained (their LGKM(4)) before stB

    if (pf) stB(bslot, 0, t + 2);                // vm +2
    rdA(As, 2, av0);                             // ks1 + ks2 in flight
    LGKM(4);                                     // ks1 ready
    mfma8(av1, 1);
    if (pf) stB(bslot, 1, t + 2);                // vm +2
    rdA(As, 3, av1);                             // ks2 + ks3 in flight
    LGKM(4);                                     // ks2 ready
    mfma8(av0, 2);
    LGKM(0);                                     // ks3 ready
    mfma8(av1, 3);

    // boundary: publish tile t+1 (counted; never drain in steady state)
    if (pf)              { VMCNT(6); }
    else if (t + 1 < NT) { VMCNT(0); }
    if (t + 1 < NT) BARRIER();                   // bar2

    aslot = (aslot == 2) ? 0 : aslot + 1;
    bslot ^= 1;
  }

  // epilogue: 32x32 C/D layout col=lane&31, row=(reg&3)+8*(reg>>2)+4*(lane>>5)
  const int colg0 = bn * BN + wn * 64 + lane31;
  const int rowg0 = bm * BM + wm * 128 + 4 * (lane >> 5);
#pragma unroll
  for (int ni = 0; ni < 2; ++ni) {
    const int colg = colg0 + ni * 32;
    const float bvs = bias[colg];
#pragma unroll
    for (int mi = 0; mi < 4; ++mi) {
      const int rowb = rowg0 + mi * 32;
#pragma unroll
      for (int r = 0; r < 16; ++r) {
        const int row = rowb + (r & 3) + 8 * (r >> 2);
        C[(size_t)row * OUT_F + colg] = acc[mi][ni][r] + bvs;
      }
    }
  }
}

// ---------------- fallback (only if ws too small) ----------------

__global__ void fallback_kernel(const float* __restrict__ x,
                                const float* __restrict__ wmu,
                                const float* __restrict__ wrho,
                                const float* __restrict__ weps,
                                const float* __restrict__ bmu,
                                const float* __restrict__ brho,
                                const float* __restrict__ beps,
                                float* __restrict__ out) {
  int o = blockIdx.x * blockDim.x + threadIdx.x;
  int t = blockIdx.y;
  float s = 0.f;
  const float* xr = x + (size_t)t * IN_F;
  const float* wm = wmu + (size_t)o * IN_F;
  const float* wr = wrho + (size_t)o * IN_F;
  const float* we = weps + (size_t)o * IN_F;
  for (int k = 0; k < IN_F; ++k)
    s += xr[k] * fmaf(softplus_f(wr[k]), we[k], wm[k]);
  out[(size_t)t * OUT_F + o] = s + fmaf(softplus_f(brho[o]), beps[o], bmu[o]);
}

// ---------------- launch ----------------

extern "C" void kernel_launch(void* const* d_in, const int* in_sizes, int n_in,
                              void* d_out, int out_size, void* d_ws, size_t ws_size,
                              hipStream_t stream) {
  const float* x    = (const float*)d_in[0];
  const float* wmu  = (const float*)d_in[1];
  const float* wrho = (const float*)d_in[2];
  const float* bmu  = (const float*)d_in[3];
  const float* brho = (const float*)d_in[4];
  const float* weps = (const float*)d_in[5];
  const float* beps = (const float*)d_in[6];
  float* out = (float*)d_out;

  const size_t xb_off   = 0;
  const size_t wb_off   = (size_t)TOKENS * IN_F * 2;            // 64 MB
  const size_t bias_off = wb_off + (size_t)OUT_F * IN_F * 2;    // +32 MB
  const size_t needed   = bias_off + (size_t)OUT_F * 4;

  if (ws_size < needed) {
    dim3 g(OUT_F / 256, TOKENS);
    hipLaunchKernelGGL(fallback_kernel, g, dim3(256), 0, stream,
                       x, wmu, wrho, weps, bmu, brho, beps, out);
    return;
  }

  unsigned short* xb = (unsigned short*)((char*)d_ws + xb_off);
  unsigned short* wb = (unsigned short*)((char*)d_ws + wb_off);
  float* bias = (float*)((char*)d_ws + bias_off);

  hipLaunchKernelGGL(prep_kernel, dim3(2048), dim3(256), 0, stream,
                     x, wmu, wrho, weps, bmu, brho, beps, xb, wb, bias);

  hipLaunchKernelGGL(gemm_bt_kernel,
                     dim3((TOKENS / BM) * (OUT_F / BN)), dim3(THREADS), 0, stream,
                     xb, wb, bias, out);
}